// Round 2
// baseline (1986.771 us; speedup 1.0000x reference)
//
#include <hip/hip_runtime.h>
#include <hip/hip_bf16.h>
#include <cstddef>

// Problem constants (match reference)
#define V_ 32000
#define E_ 128
#define H_ 128
#define B_ 256
#define T_ 32
#define G4_ 512   // 4*H

typedef __bf16 bf16x8 __attribute__((ext_vector_type(8)));
typedef float  f32x4  __attribute__((ext_vector_type(4)));

// ---- hand-rolled RNE fp32<->bf16 (avoids hip_bf16.h API drift) ------------
__device__ __forceinline__ unsigned short f2bf(float f) {
    unsigned u = __builtin_bit_cast(unsigned, f);
    unsigned r = (u + 0x7fffu + ((u >> 16) & 1u)) >> 16;   // round-nearest-even
    return (unsigned short)r;
}
__device__ __forceinline__ float bf2f(unsigned short b) {
    unsigned u = ((unsigned)b) << 16;
    return __builtin_bit_cast(float, u);
}

// ---------------------------------------------------------------------------
// Kernel 0: split fc_w fp32 -> (hi, lo) bf16. hi = RNE(f); lo = RNE(f - hi).
// ---------------------------------------------------------------------------
__global__ __launch_bounds__(256) void cvt_split(
    const float* __restrict__ src, unsigned short* __restrict__ hi,
    unsigned short* __restrict__ lo, int n4)
{
    int i = blockIdx.x * 256 + threadIdx.x;
    if (i >= n4) return;
    float4 v = ((const float4*)src)[i];
    ushort4 h, l;
    h.x = f2bf(v.x); l.x = f2bf(v.x - bf2f(h.x));
    h.y = f2bf(v.y); l.y = f2bf(v.y - bf2f(h.y));
    h.z = f2bf(v.z); l.z = f2bf(v.z - bf2f(h.z));
    h.w = f2bf(v.w); l.w = f2bf(v.w - bf2f(h.w));
    ((ushort4*)hi)[i] = h;
    ((ushort4*)lo)[i] = l;
}

// ---------------------------------------------------------------------------
// Kernel 1: LSTM recurrence (fp32 throughout; only the hs output is split to
// bf16 hi/lo for the MFMA FC). One block = BPB batch rows for all T steps;
// h,c live in LDS. Recurrence is independent per batch row -> no grid sync.
// ---------------------------------------------------------------------------
#define BPB 4
__global__ __launch_bounds__(512) void lstm_rec(
    const int*   __restrict__ seq,    // [B,T]
    const float* __restrict__ h0,     // [B,H]
    const float* __restrict__ c0,     // [B,H]
    const float* __restrict__ emb,    // [V,E]
    const float* __restrict__ w_ih,   // [4H,E]
    const float* __restrict__ w_hh,   // [4H,H]
    const float* __restrict__ b_ih,   // [4H]
    const float* __restrict__ b_hh,   // [4H]
    unsigned short* __restrict__ hs_hi, // [B*T,H] bf16 bits (row = b*T+t)
    unsigned short* __restrict__ hs_lo, // [B*T,H]
    float* __restrict__ hc_out)         // [2*B*H] (h_f then c_f)
{
    __shared__ float sx[BPB][H_];
    __shared__ float sh[BPB][H_];
    __shared__ float sc[BPB][H_];
    __shared__ float sg[BPB][G4_];

    const int tid = threadIdx.x;          // 0..511
    const int b0  = blockIdx.x * BPB;

    for (int i = tid; i < BPB * H_; i += 512) {
        int bb = i >> 7, n = i & 127;
        sh[bb][n] = h0[(b0 + bb) * H_ + n];
        sc[bb][n] = c0[(b0 + bb) * H_ + n];
    }

    const int j = tid;                    // gate row 0..511
    const float bias_j = b_ih[j] + b_hh[j];
    const float4* wi = (const float4*)(w_ih + (size_t)j * E_);
    const float4* wh = (const float4*)(w_hh + (size_t)j * H_);

    __syncthreads();

    for (int t = 0; t < T_; ++t) {
        if (tid < 128) {
            int bb = tid >> 5, q = tid & 31;
            int tok = seq[(b0 + bb) * T_ + t];
            ((float4*)sx[bb])[q] = ((const float4*)(emb + (size_t)tok * E_))[q];
        }
        __syncthreads();

        float acc[BPB];
        #pragma unroll
        for (int bb = 0; bb < BPB; ++bb) acc[bb] = bias_j;
        #pragma unroll 4
        for (int k4 = 0; k4 < H_ / 4; ++k4) {
            float4 w = wi[k4];
            #pragma unroll
            for (int bb = 0; bb < BPB; ++bb) {
                float4 x = ((const float4*)sx[bb])[k4];
                acc[bb] += w.x * x.x + w.y * x.y + w.z * x.z + w.w * x.w;
            }
            float4 v = wh[k4];
            #pragma unroll
            for (int bb = 0; bb < BPB; ++bb) {
                float4 h = ((const float4*)sh[bb])[k4];
                acc[bb] += v.x * h.x + v.y * h.y + v.z * h.z + v.w * h.w;
            }
        }
        #pragma unroll
        for (int bb = 0; bb < BPB; ++bb) sg[bb][j] = acc[bb];
        __syncthreads();

        {
            int bb = tid >> 7, n = tid & 127;
            float ig = sg[bb][n];
            float fg = sg[bb][128 + n];
            float gg = sg[bb][256 + n];
            float og = sg[bb][384 + n];
            float i_ = 1.0f / (1.0f + expf(-ig));
            float f_ = 1.0f / (1.0f + expf(-fg));
            float g_ = tanhf(gg);
            float o_ = 1.0f / (1.0f + expf(-og));
            float cn = f_ * sc[bb][n] + i_ * g_;
            float hn = o_ * tanhf(cn);
            sc[bb][n] = cn;
            sh[bb][n] = hn;
            size_t idx = ((size_t)(b0 + bb) * T_ + t) * H_ + n;
            unsigned short hh = f2bf(hn);
            hs_hi[idx] = hh;
            hs_lo[idx] = f2bf(hn - bf2f(hh));
        }
        __syncthreads();
    }

    for (int i = tid; i < BPB * H_; i += 512) {
        int bb = i >> 7, n = i & 127;
        hc_out[(b0 + bb) * H_ + n]           = sh[bb][n];
        hc_out[B_ * H_ + (b0 + bb) * H_ + n] = sc[bb][n];
    }
}

// ---------------------------------------------------------------------------
// Kernel 2: FC via split-bf16 MFMA. C[m][n] = sum_k A[m][k]B[n][k] + bias[n].
// M=8192, N=32000, K=128. Block 256 thr = 4 waves (2x2), wave = 64x64 out.
// No LDS: fragments load straight from global (A 4MB / B 16MB are L2/L3
// resident; each 16B/lane load covers 16 full 64B lines). 3-product split:
// D += Ah*Bh + Ah*Bl + Al*Bh  (error ~2^-16 relative).
// k-map robustness: A and B use the IDENTICAL lane->(row, k-chunk) pattern,
// so any HW k-slot permutation applies to both operands and cancels.
// ---------------------------------------------------------------------------
#define GTM 128
#define GTN 128
__global__ __launch_bounds__(256) void fc_mfma(
    const unsigned short* __restrict__ Ah, const unsigned short* __restrict__ Al,
    const unsigned short* __restrict__ Bh, const unsigned short* __restrict__ Bl,
    const float* __restrict__ bias, float* __restrict__ C)
{
    // XCD-aware swizzle: 16000 blocks = 8 xcd * 8 mt * 250 nt. Each XCD owns
    // a contiguous 8-mt band; within it, the 8 blocks of one nt are adjacent
    // so the 64KB B-tile and the 512KB A-band stay L2-resident.
    int b   = blockIdx.x;
    int xcd = b & 7;
    int idx = b >> 3;
    int mt  = xcd * 8 + (idx & 7);       // 0..63
    int nt  = idx >> 3;                  // 0..249
    int m0  = mt * GTM, n0 = nt * GTN;

    int tid  = threadIdx.x;
    int wid  = tid >> 6;
    int lane = tid & 63;
    int mw = m0 + (wid >> 1) * 64;
    int nw = n0 + (wid & 1) * 64;
    int r  = lane & 15;
    int ko = (lane >> 4) * 8;            // k-chunk within 32

    f32x4 acc[4][4];
    #pragma unroll
    for (int i = 0; i < 4; ++i)
        #pragma unroll
        for (int j = 0; j < 4; ++j)
            acc[i][j] = (f32x4){0.f, 0.f, 0.f, 0.f};

    for (int kk = 0; kk < 128; kk += 32) {
        bf16x8 ah[4], al[4], bh[4], bl[4];
        #pragma unroll
        for (int s = 0; s < 4; ++s) {
            size_t arow = (size_t)(mw + s * 16 + r) * 128 + kk + ko;
            size_t brow = (size_t)(nw + s * 16 + r) * 128 + kk + ko;
            ah[s] = *(const bf16x8*)(Ah + arow);
            al[s] = *(const bf16x8*)(Al + arow);
            bh[s] = *(const bf16x8*)(Bh + brow);
            bl[s] = *(const bf16x8*)(Bl + brow);
        }
        #pragma unroll
        for (int i = 0; i < 4; ++i)
            #pragma unroll
            for (int j = 0; j < 4; ++j) {
                acc[i][j] = __builtin_amdgcn_mfma_f32_16x16x32_bf16(ah[i], bh[j], acc[i][j], 0, 0, 0);
                acc[i][j] = __builtin_amdgcn_mfma_f32_16x16x32_bf16(ah[i], bl[j], acc[i][j], 0, 0, 0);
                acc[i][j] = __builtin_amdgcn_mfma_f32_16x16x32_bf16(al[i], bh[j], acc[i][j], 0, 0, 0);
            }
    }

    // Epilogue: verified C/D layout (m89/m91): col = lane&15, row = (lane>>4)*4+q
    int rb = (lane >> 4) * 4;
    #pragma unroll
    for (int j = 0; j < 4; ++j) {
        float bv = bias[nw + j * 16 + r];
        #pragma unroll
        for (int i = 0; i < 4; ++i) {
            #pragma unroll
            for (int q = 0; q < 4; ++q) {
                C[(size_t)(mw + i * 16 + rb + q) * V_ + nw + j * 16 + r] = acc[i][j][q] + bv;
            }
        }
    }
}

// ---------------------------------------------------------------------------
extern "C" void kernel_launch(void* const* d_in, const int* in_sizes, int n_in,
                              void* d_out, int out_size, void* d_ws, size_t ws_size,
                              hipStream_t stream) {
    const int*   seq  = (const int*)  d_in[0];
    const float* h0   = (const float*)d_in[1];
    const float* c0   = (const float*)d_in[2];
    const float* emb  = (const float*)d_in[3];
    const float* w_ih = (const float*)d_in[4];
    const float* w_hh = (const float*)d_in[5];
    const float* b_ih = (const float*)d_in[6];
    const float* b_hh = (const float*)d_in[7];
    const float* fc_w = (const float*)d_in[8];
    const float* fc_b = (const float*)d_in[9];

    float* out    = (float*)d_out;                       // [B*T, V] then h_f, c_f
    float* hc_out = out + (size_t)B_ * T_ * V_;

    // Workspace layout (bf16 bit arrays): B_hi, B_lo [32000*128]; A_hi, A_lo [8192*128]
    unsigned short* B_hi = (unsigned short*)d_ws;
    unsigned short* B_lo = B_hi + (size_t)V_ * H_;
    unsigned short* A_hi = B_lo + (size_t)V_ * H_;
    unsigned short* A_lo = A_hi + (size_t)B_ * T_ * H_;
    // total: 2*4.096M + 2*1.048M ushort = ~20.6 MB

    const int n4 = V_ * H_ / 4;                          // 1,024,000 float4
    cvt_split<<<(n4 + 255) / 256, 256, 0, stream>>>(fc_w, B_hi, B_lo, n4);

    lstm_rec<<<B_ / BPB, 512, 0, stream>>>(seq, h0, c0, emb, w_ih, w_hh,
                                           b_ih, b_hh, A_hi, A_lo, hc_out);

    const int grid = (B_ * T_ / GTM) * (V_ / GTN);       // 64 * 250 = 16000
    fc_mfma<<<grid, 256, 0, stream>>>(A_hi, A_lo, B_hi, B_lo, fc_b, out);
}